// Round 1
// baseline (626.546 us; speedup 1.0000x reference)
//
#include <hip/hip_runtime.h>
#include <math.h>

namespace {
constexpr int kC  = 256;   // channels
constexpr int kW  = 48;    // width
constexpr int kM  = 2304;  // tokens = 48*48
constexpr int kB  = 2;     // batch
constexpr int kDH = 32;    // head dim
}

// ---- BN scale/shift precompute -------------------------------------------
__global__ void prep_bn(const float* __restrict__ gamma, const float* __restrict__ beta,
                        const float* __restrict__ rmean, const float* __restrict__ rvar,
                        float* __restrict__ bninv, float* __restrict__ bnshift) {
    int c = threadIdx.x;
    float iv = gamma[c] / sqrtf(rvar[c] + 1e-5f);
    bninv[c] = iv;
    bnshift[c] = beta[c] - rmean[c] * iv;
}

// ---- 1x1 conv with fused BN: O[b][m][o] = sum_c xn[b][c][m] * W[o][c] ----
// x layout (B,C,M) row-major, output (B,M,C) token-major.
__global__ __launch_bounds__(256) void conv_in(const float* __restrict__ x,
                                               const float* __restrict__ Wm,
                                               const float* __restrict__ bninv,
                                               const float* __restrict__ bnshift,
                                               float* __restrict__ O) {
    __shared__ float Xs[32][36];   // [c][m], padded for b128 alignment
    __shared__ float Ws[32][36];   // [o][c]
    int t = threadIdx.x;
    int lo = t & 31, hi = t >> 5;
    int m0 = blockIdx.x * 32, o0 = blockIdx.y * 32, b = blockIdx.z;
    float acc[4] = {0.f, 0.f, 0.f, 0.f};  // 4 m-rows, o = lo
    for (int kc = 0; kc < kC; kc += 32) {
        #pragma unroll
        for (int i = 0; i < 4; i++) {
            int c = hi + i * 8;
            Xs[c][lo] = x[(size_t)(b * kC + kc + c) * kM + m0 + lo] * bninv[kc + c] + bnshift[kc + c];
            Ws[c][lo] = Wm[(o0 + c) * kC + kc + lo];
        }
        __syncthreads();
        float wreg[32];
        #pragma unroll
        for (int c0 = 0; c0 < 32; c0 += 4) {
            float4 w4 = *reinterpret_cast<const float4*>(&Ws[lo][c0]);
            wreg[c0] = w4.x; wreg[c0 + 1] = w4.y; wreg[c0 + 2] = w4.z; wreg[c0 + 3] = w4.w;
        }
        #pragma unroll
        for (int c = 0; c < 32; c++) {
            float4 xv = *reinterpret_cast<const float4*>(&Xs[c][hi * 4]);
            acc[0] += xv.x * wreg[c];
            acc[1] += xv.y * wreg[c];
            acc[2] += xv.z * wreg[c];
            acc[3] += xv.w * wreg[c];
        }
        __syncthreads();
    }
    #pragma unroll
    for (int i = 0; i < 4; i++)
        O[(size_t)(b * kM + m0 + hi * 4 + i) * kC + o0 + lo] = acc[i];  // coalesced along o
}

// ---- zr = l2n(z) + l2n(r), in place on Z (B,M,C) -------------------------
__global__ __launch_bounds__(256) void zr_kernel(float* __restrict__ Z) {
    int bm = blockIdx.x;            // b*M + m
    int c = threadIdx.x;            // 0..255
    int m = bm % kM;
    float zv = Z[(size_t)bm * kC + c];
    float ss = zv * zv;
    #pragma unroll
    for (int k = 32; k >= 1; k >>= 1) ss += __shfl_xor(ss, k);
    __shared__ float part[4];
    if ((c & 63) == 0) part[c >> 6] = ss;
    __syncthreads();
    float tot = part[0] + part[1] + part[2] + part[3];
    float zinv = 1.0f / sqrtf(tot + 1e-6f);
    // positional encoding value for (c, m); ||r||^2 == 128 exactly
    int yrow = m / kW, xcol = m % kW;
    int cc  = (c < 128) ? c : (c - 128);
    int pos = (c < 128) ? xcol : yrow;
    // div = exp(2i * (-ln(10000)/128)), computed like the fp32 reference
    float dv = __expf((float)(cc & ~1) * (float)(-9.210340371976184 / 128.0));
    float pd = (float)pos * dv;
    float rv = (c & 1) ? cosf(pd) : sinf(pd);
    const float RINV = 1.0f / sqrtf(128.0f + 1e-6f);
    Z[(size_t)bm * kC + c] = zv * zinv + rv * RINV;
}

// ---- fused flash attention per (m-tile, head, b) -------------------------
// logits[m,n] = (1/sqrt(32)) * sum_c V[b,m,hc] * ZR[b,n,hc]; softmax over n;
// Y[b,m,hc] = sum_n A[m,n] * Q[b,n,hc]
__global__ __launch_bounds__(256) void flash_attn(const float* __restrict__ V,
                                                  const float* __restrict__ ZR,
                                                  const float* __restrict__ Q,
                                                  float* __restrict__ Y) {
    __shared__ float Vs[32][36];
    __shared__ float ZRs[64][36];
    __shared__ float Qs[64][36];
    __shared__ float Ps[32][68];
    int t = threadIdx.x;
    int lo = t & 31, hi = t >> 5;
    int m0 = blockIdx.x * 32;
    int h = blockIdx.y;
    int b = blockIdx.z;
    const float SCALE = 0.17677669529663687f;  // 1/sqrt(32)
    #pragma unroll
    for (int i = 0; i < 4; i++) {
        int m = hi + i * 8;
        Vs[m][lo] = V[(size_t)(b * kM + m0 + m) * kC + h * kDH + lo] * SCALE;
    }
    __syncthreads();
    int mi = t >> 3;  // row 0..31 (8 lanes per row, row group inside one wave)
    int r = t & 7;
    float vreg[32];
    #pragma unroll
    for (int c0 = 0; c0 < 32; c0 += 4) {
        float4 v4 = *reinterpret_cast<const float4*>(&Vs[mi][c0]);
        vreg[c0] = v4.x; vreg[c0 + 1] = v4.y; vreg[c0 + 2] = v4.z; vreg[c0 + 3] = v4.w;
    }
    float acc[4] = {0.f, 0.f, 0.f, 0.f};
    float mval = -INFINITY, lsum = 0.0f;

    for (int n0 = 0; n0 < kM; n0 += 64) {
        __syncthreads();  // previous PV done with ZRs/Qs
        #pragma unroll
        for (int j = 0; j < 8; j++) {
            int n = hi + j * 8;
            size_t base = (size_t)(b * kM + n0 + n) * kC + h * kDH + lo;
            ZRs[n][lo] = ZR[base];
            Qs[n][lo] = Q[base];
        }
        __syncthreads();
        // S = V . ZR^T  (8 cols per thread)
        float s[8];
        #pragma unroll
        for (int j = 0; j < 8; j++) {
            int n = r + j * 8;
            float a0 = 0, a1 = 0, a2 = 0, a3 = 0;
            #pragma unroll
            for (int c0 = 0; c0 < 32; c0 += 4) {
                float4 zv = *reinterpret_cast<const float4*>(&ZRs[n][c0]);
                a0 += vreg[c0] * zv.x;
                a1 += vreg[c0 + 1] * zv.y;
                a2 += vreg[c0 + 2] * zv.z;
                a3 += vreg[c0 + 3] * zv.w;
            }
            s[j] = (a0 + a1) + (a2 + a3);
        }
        // online softmax
        float tmax = s[0];
        #pragma unroll
        for (int j = 1; j < 8; j++) tmax = fmaxf(tmax, s[j]);
        tmax = fmaxf(tmax, __shfl_xor(tmax, 1));
        tmax = fmaxf(tmax, __shfl_xor(tmax, 2));
        tmax = fmaxf(tmax, __shfl_xor(tmax, 4));
        float nm = fmaxf(mval, tmax);
        float resc = __expf(mval - nm);
        float ps = 0.f;
        #pragma unroll
        for (int j = 0; j < 8; j++) { s[j] = __expf(s[j] - nm); ps += s[j]; }
        ps += __shfl_xor(ps, 1);
        ps += __shfl_xor(ps, 2);
        ps += __shfl_xor(ps, 4);
        lsum = lsum * resc + ps;
        mval = nm;
        #pragma unroll
        for (int k = 0; k < 4; k++) acc[k] *= resc;
        #pragma unroll
        for (int j = 0; j < 8; j++) Ps[mi][r + j * 8] = s[j];
        __syncthreads();
        // O += P @ Q_tile  (4 channels per thread: ch = r*4+k)
        #pragma unroll
        for (int n = 0; n < 64; n += 4) {
            float4 p = *reinterpret_cast<const float4*>(&Ps[mi][n]);
            #pragma unroll
            for (int d = 0; d < 4; d++) {
                float4 qv = *reinterpret_cast<const float4*>(&Qs[n + d][r * 4]);
                float pd = (&p.x)[d];
                acc[0] += pd * qv.x;
                acc[1] += pd * qv.y;
                acc[2] += pd * qv.z;
                acc[3] += pd * qv.w;
            }
        }
    }
    float li = 1.0f / lsum;
    #pragma unroll
    for (int k = 0; k < 4; k++)
        Y[(size_t)(b * kM + m0 + mi) * kC + h * kDH + r * 4 + k] = acc[k] * li;
}

// ---- output conv: out[b][o][m] = sum_c W[o][c] * Y[b][m][c] --------------
__global__ __launch_bounds__(256) void conv_out(const float* __restrict__ Yb,
                                                const float* __restrict__ Wm,
                                                float* __restrict__ out) {
    __shared__ float Ys[32][36];   // [m][c]
    __shared__ float Ws[32][36];   // [o][c]
    int t = threadIdx.x;
    int lo = t & 31, hi = t >> 5;
    int m0 = blockIdx.x * 32, o0 = blockIdx.y * 32, b = blockIdx.z;
    float acc[4] = {0.f, 0.f, 0.f, 0.f};  // 4 o-rows, m = lo
    for (int kc = 0; kc < kC; kc += 32) {
        #pragma unroll
        for (int i = 0; i < 4; i++) {
            int mrow = hi + i * 8;
            Ys[mrow][lo] = Yb[(size_t)(b * kM + m0 + mrow) * kC + kc + lo];
            Ws[mrow][lo] = Wm[(o0 + mrow) * kC + kc + lo];
        }
        __syncthreads();
        float yreg[32];
        #pragma unroll
        for (int c0 = 0; c0 < 32; c0 += 4) {
            float4 y4 = *reinterpret_cast<const float4*>(&Ys[lo][c0]);
            yreg[c0] = y4.x; yreg[c0 + 1] = y4.y; yreg[c0 + 2] = y4.z; yreg[c0 + 3] = y4.w;
        }
        #pragma unroll
        for (int i = 0; i < 4; i++) {
            int o = hi * 4 + i;
            float a = 0.f;
            #pragma unroll
            for (int c0 = 0; c0 < 32; c0 += 4) {
                float4 w4 = *reinterpret_cast<const float4*>(&Ws[o][c0]);
                a += yreg[c0] * w4.x + yreg[c0 + 1] * w4.y + yreg[c0 + 2] * w4.z + yreg[c0 + 3] * w4.w;
            }
            acc[i] += a;
        }
        __syncthreads();
    }
    #pragma unroll
    for (int i = 0; i < 4; i++)
        out[(size_t)(b * kC + o0 + hi * 4 + i) * kM + m0 + lo] = acc[i];  // coalesced along m
}

extern "C" void kernel_launch(void* const* d_in, const int* in_sizes, int n_in,
                              void* d_out, int out_size, void* d_ws, size_t ws_size,
                              hipStream_t stream) {
    const float* x     = (const float*)d_in[0];
    const float* gamma = (const float*)d_in[1];
    const float* beta  = (const float*)d_in[2];
    const float* rmean = (const float*)d_in[3];
    const float* rvar  = (const float*)d_in[4];
    const float* v_w   = (const float*)d_in[5];
    const float* z_w   = (const float*)d_in[6];
    const float* q_w   = (const float*)d_in[7];
    const float* o_w   = (const float*)d_in[8];
    float* out = (float*)d_out;

    float* ws = (float*)d_ws;
    const size_t BMC = (size_t)kB * kM * kC;  // 1,179,648
    float* bninv   = ws;
    float* bnshift = ws + 256;
    float* Vb = ws + 512;
    float* Zb = Vb + BMC;
    float* Qb = Zb + BMC;
    float* Yb = Qb + BMC;   // total ~18.9 MB

    prep_bn<<<dim3(1), dim3(256), 0, stream>>>(gamma, beta, rmean, rvar, bninv, bnshift);
    dim3 gconv(kM / 32, kC / 32, kB);
    conv_in<<<gconv, dim3(256), 0, stream>>>(x, v_w, bninv, bnshift, Vb);
    conv_in<<<gconv, dim3(256), 0, stream>>>(x, z_w, bninv, bnshift, Zb);
    conv_in<<<gconv, dim3(256), 0, stream>>>(x, q_w, bninv, bnshift, Qb);
    zr_kernel<<<dim3(kB * kM), dim3(256), 0, stream>>>(Zb);
    flash_attn<<<dim3(kM / 32, 8, kB), dim3(256), 0, stream>>>(Vb, Zb, Qb, Yb);
    conv_out<<<gconv, dim3(256), 0, stream>>>(Yb, o_w, out);
}

// Round 5
// 150.842 us; speedup vs baseline: 4.1537x; 4.1537x over previous
//
#include <hip/hip_runtime.h>
#include <hip/hip_bf16.h>
#include <math.h>

namespace {
constexpr int kC  = 256;   // channels
constexpr int kW  = 48;    // width
constexpr int kM  = 2304;  // tokens = 48*48
constexpr int kB  = 2;     // batch
constexpr int kDH = 32;    // head dim
constexpr int kH  = 8;     // heads
}

typedef float  f32x4  __attribute__((ext_vector_type(4)));
typedef __bf16 bf16x8 __attribute__((ext_vector_type(8)));

// D = A*B + C, bf16 16x16x32, compiler-managed hazards.
// A: row=lane&15 ; B: col=lane&15 ; D: col=lane&15, row=(lane>>4)*4+reg
__device__ __forceinline__ f32x4 mfma16(bf16x8 a, bf16x8 b, f32x4 c) {
    return __builtin_amdgcn_mfma_f32_16x16x32_bf16(a, b, c, 0, 0, 0);
}

// ---- BN scale/shift precompute -------------------------------------------
__global__ void prep_bn(const float* __restrict__ gamma, const float* __restrict__ beta,
                        const float* __restrict__ rmean, const float* __restrict__ rvar,
                        float* __restrict__ bninv, float* __restrict__ bnshift) {
    int c = threadIdx.x;
    float iv = gamma[c] / sqrtf(rvar[c] + 1e-5f);
    bninv[c] = iv;
    bnshift[c] = beta[c] - rmean[c] * iv;
}

// ---- 1x1 conv with fused BN: O[b][m][o] = sum_c xn[b][c][m] * W[o][c] ----
// MODE 0: fp32 (B,M,C)               (z path, pre-l2norm)
// MODE 1: bf16 (B,M,C) * 1/sqrt(32)  (v path, pre-scaled for logits)
// MODE 2: bf16 (B,h,dh,M) transposed (q path, PV A-operand layout)
template<int MODE>
__global__ __launch_bounds__(256) void conv_in(const float* __restrict__ x,
                                               const float* __restrict__ Wm,
                                               const float* __restrict__ bninv,
                                               const float* __restrict__ bnshift,
                                               void* __restrict__ Ovoid) {
    __shared__ float Xs[32][36];   // [c][m]
    __shared__ float Ws[32][36];   // [o][c]
    int t = threadIdx.x;
    int lo = t & 31, hi = t >> 5;
    int m0 = blockIdx.x * 32, o0 = blockIdx.y * 32, b = blockIdx.z;
    float acc[4] = {0.f, 0.f, 0.f, 0.f};  // 4 m-rows, o = lo
    for (int kc = 0; kc < kC; kc += 32) {
        #pragma unroll
        for (int i = 0; i < 4; i++) {
            int c = hi + i * 8;
            Xs[c][lo] = x[(size_t)(b * kC + kc + c) * kM + m0 + lo] * bninv[kc + c] + bnshift[kc + c];
            Ws[c][lo] = Wm[(o0 + c) * kC + kc + lo];
        }
        __syncthreads();
        float wreg[32];
        #pragma unroll
        for (int c0 = 0; c0 < 32; c0 += 4) {
            float4 w4 = *reinterpret_cast<const float4*>(&Ws[lo][c0]);
            wreg[c0] = w4.x; wreg[c0 + 1] = w4.y; wreg[c0 + 2] = w4.z; wreg[c0 + 3] = w4.w;
        }
        #pragma unroll
        for (int c = 0; c < 32; c++) {
            float4 xv = *reinterpret_cast<const float4*>(&Xs[c][hi * 4]);
            acc[0] += xv.x * wreg[c];
            acc[1] += xv.y * wreg[c];
            acc[2] += xv.z * wreg[c];
            acc[3] += xv.w * wreg[c];
        }
        __syncthreads();
    }
    if constexpr (MODE == 0) {
        float* O = (float*)Ovoid;
        #pragma unroll
        for (int i = 0; i < 4; i++)
            O[(size_t)(b * kM + m0 + hi * 4 + i) * kC + o0 + lo] = acc[i];
    } else if constexpr (MODE == 1) {
        __hip_bfloat16* O = (__hip_bfloat16*)Ovoid;
        const float SCALE = 0.17677669529663687f;  // 1/sqrt(32)
        #pragma unroll
        for (int i = 0; i < 4; i++)
            O[(size_t)(b * kM + m0 + hi * 4 + i) * kC + o0 + lo] = __float2bfloat16(acc[i] * SCALE);
    } else {
        __hip_bfloat16* O = (__hip_bfloat16*)Ovoid;
        int hh = (o0 + lo) >> 5, d = (o0 + lo) & 31;
        #pragma unroll
        for (int i = 0; i < 4; i++)
            O[((size_t)(b * kH + hh) * kDH + d) * kM + m0 + hi * 4 + i] = __float2bfloat16(acc[i]);
    }
}

// ---- zr = l2n(z) + l2n(r): fp32 in, bf16 out (B,M,C) ---------------------
__global__ __launch_bounds__(256) void zr_kernel(const float* __restrict__ Z,
                                                 __hip_bfloat16* __restrict__ ZRo) {
    int bm = blockIdx.x;            // b*M + m
    int c = threadIdx.x;            // 0..255
    int m = bm % kM;
    float zv = Z[(size_t)bm * kC + c];
    float ss = zv * zv;
    #pragma unroll
    for (int k = 32; k >= 1; k >>= 1) ss += __shfl_xor(ss, k);
    __shared__ float part[4];
    if ((c & 63) == 0) part[c >> 6] = ss;
    __syncthreads();
    float tot = part[0] + part[1] + part[2] + part[3];
    float zinv = 1.0f / sqrtf(tot + 1e-6f);
    int yrow = m / kW, xcol = m % kW;
    int cc  = (c < 128) ? c : (c - 128);
    int pos = (c < 128) ? xcol : yrow;
    float dv = __expf((float)(cc & ~1) * (float)(-9.210340371976184 / 128.0));
    float pd = (float)pos * dv;
    float rv = (c & 1) ? cosf(pd) : sinf(pd);
    const float RINV = 1.0f / sqrtf(128.0f + 1e-6f);
    ZRo[(size_t)bm * kC + c] = __float2bfloat16(zv * zinv + rv * RINV);
}

// ---- MFMA flash attention: 1 wave per 32 q-rows per (b,h) ----------------
// S^T tile = mfma(A=ZR rows(n), B=V rows(m));  Y^T = mfma(A=Qt rows(dh), B=P^T from LDS)
__global__ __launch_bounds__(64) void flash_attn_mfma(
    const __hip_bfloat16* __restrict__ V,    // (B,M,C) bf16, pre-scaled by 1/sqrt(32)
    const __hip_bfloat16* __restrict__ ZR,   // (B,M,C) bf16
    const __hip_bfloat16* __restrict__ Qt,   // (B,h,dh,M) bf16
    float* __restrict__ Y)                   // (B,M,C) fp32
{
    __shared__ __hip_bfloat16 P_lds[32][72];   // [m_local][n_local], pitch 144B
    const int t = threadIdx.x;
    const int li = t & 15, g = t >> 4;
    const int m0 = blockIdx.x * 32;
    const int h = blockIdx.y, b = blockIdx.z;

    const f32x4 zero4 = {0.f, 0.f, 0.f, 0.f};

    bf16x8 vfrag[2];
    #pragma unroll
    for (int mt = 0; mt < 2; mt++)
        vfrag[mt] = *reinterpret_cast<const bf16x8*>(
            V + ((size_t)(b * kM + m0 + mt * 16 + li) * kC + h * kDH + g * 8));

    const __hip_bfloat16* zrp = ZR + ((size_t)b * kM * kC + h * kDH + g * 8);
    const __hip_bfloat16* qtp = Qt + ((size_t)(b * kH + h) * kDH) * (size_t)kM + g * 8;

    f32x4 acc[2][2];   // [mt][dt]: Y^T tiles
    #pragma unroll
    for (int mt = 0; mt < 2; mt++)
        #pragma unroll
        for (int dt = 0; dt < 2; dt++) acc[mt][dt] = zero4;
    float mval[2] = {-INFINITY, -INFINITY};
    float lsum[2] = {0.f, 0.f};

    // preload first KV tile fragments
    bf16x8 za[4], qa[2][2];
    #pragma unroll
    for (int tl = 0; tl < 4; tl++)
        za[tl] = *reinterpret_cast<const bf16x8*>(zrp + (size_t)(tl * 16 + li) * kC);
    #pragma unroll
    for (int dt = 0; dt < 2; dt++)
        #pragma unroll
        for (int kc = 0; kc < 2; kc++)
            qa[dt][kc] = *reinterpret_cast<const bf16x8*>(qtp + (size_t)(dt * 16 + li) * kM + kc * 32);

    for (int n0 = 0; n0 < kM; n0 += 64) {
        // S^T tiles: st[mt][tl]: row n = tl*16+4g+r, col m = mt*16+li
        f32x4 st[2][4];
        #pragma unroll
        for (int mt = 0; mt < 2; mt++)
            #pragma unroll
            for (int tl = 0; tl < 4; tl++)
                st[mt][tl] = mfma16(za[tl], vfrag[mt], zero4);

        // prefetch next KV tile (wraps harmlessly on last iter)
        const int n1 = (n0 + 64 < kM) ? (n0 + 64) : 0;
        bf16x8 zn[4], qn[2][2];
        #pragma unroll
        for (int tl = 0; tl < 4; tl++)
            zn[tl] = *reinterpret_cast<const bf16x8*>(zrp + (size_t)(n1 + tl * 16 + li) * kC);
        #pragma unroll
        for (int dt = 0; dt < 2; dt++)
            #pragma unroll
            for (int kc = 0; kc < 2; kc++)
                qn[dt][kc] = *reinterpret_cast<const bf16x8*>(qtp + (size_t)(dt * 16 + li) * kM + n1 + kc * 32);

        // online softmax (row m sits at col lane&15 -> reduce over regs, tl, then g via 2 shuffles)
        #pragma unroll
        for (int mt = 0; mt < 2; mt++) {
            float rmax = st[mt][0][0];
            #pragma unroll
            for (int tl = 0; tl < 4; tl++)
                #pragma unroll
                for (int r = 0; r < 4; r++) rmax = fmaxf(rmax, st[mt][tl][r]);
            rmax = fmaxf(rmax, __shfl_xor(rmax, 16));
            rmax = fmaxf(rmax, __shfl_xor(rmax, 32));
            float nm = fmaxf(mval[mt], rmax);
            float resc = __expf(mval[mt] - nm);
            mval[mt] = nm;
            float p[4][4];
            float rsum = 0.f;
            #pragma unroll
            for (int tl = 0; tl < 4; tl++)
                #pragma unroll
                for (int r = 0; r < 4; r++) {
                    p[tl][r] = __expf(st[mt][tl][r] - nm);
                    rsum += p[tl][r];
                }
            rsum += __shfl_xor(rsum, 16);
            rsum += __shfl_xor(rsum, 32);
            lsum[mt] = lsum[mt] * resc + rsum;
            #pragma unroll
            for (int dt = 0; dt < 2; dt++) acc[mt][dt] = acc[mt][dt] * resc;
            // P^T -> LDS as [m][n] bf16, packed pair writes
            #pragma unroll
            for (int tl = 0; tl < 4; tl++)
                #pragma unroll
                for (int pr = 0; pr < 2; pr++) {
                    __hip_bfloat162 h2 = __float22bfloat162_rn(
                        make_float2(p[tl][2 * pr], p[tl][2 * pr + 1]));
                    *reinterpret_cast<__hip_bfloat162*>(
                        &P_lds[mt * 16 + li][tl * 16 + 4 * g + 2 * pr]) = h2;
                }
        }

        __syncthreads();   // RAW: P writes (all lanes) visible before cross-lane reads

        // Y^T += Qt_tile . P^T  (A from regs, B from LDS b128 reads)
        #pragma unroll
        for (int mt = 0; mt < 2; mt++)
            #pragma unroll
            for (int kc = 0; kc < 2; kc++) {
                bf16x8 pb = *reinterpret_cast<const bf16x8*>(&P_lds[mt * 16 + li][kc * 32 + g * 8]);
                #pragma unroll
                for (int dt = 0; dt < 2; dt++)
                    acc[mt][dt] = mfma16(qa[dt][kc], pb, acc[mt][dt]);
            }

        __syncthreads();   // WAR: next iter's P writes must not hoist above these reads

        #pragma unroll
        for (int tl = 0; tl < 4; tl++) za[tl] = zn[tl];
        #pragma unroll
        for (int dt = 0; dt < 2; dt++)
            #pragma unroll
            for (int kc = 0; kc < 2; kc++) qa[dt][kc] = qn[dt][kc];
    }

    #pragma unroll
    for (int mt = 0; mt < 2; mt++) {
        float linv = 1.0f / lsum[mt];
        #pragma unroll
        for (int dt = 0; dt < 2; dt++)
            #pragma unroll
            for (int r = 0; r < 4; r++)
                Y[(size_t)(b * kM + m0 + mt * 16 + li) * kC + h * kDH + dt * 16 + 4 * g + r] =
                    acc[mt][dt][r] * linv;
    }
}

// ---- output conv: out[b][o][m] = sum_c W[o][c] * Y[b][m][c] --------------
__global__ __launch_bounds__(256) void conv_out(const float* __restrict__ Yb,
                                                const float* __restrict__ Wm,
                                                float* __restrict__ out) {
    __shared__ float Ys[32][36];   // [m][c]
    __shared__ float Ws[32][36];   // [o][c]
    int t = threadIdx.x;
    int lo = t & 31, hi = t >> 5;
    int m0 = blockIdx.x * 32, o0 = blockIdx.y * 32, b = blockIdx.z;
    float acc[4] = {0.f, 0.f, 0.f, 0.f};  // 4 o-rows, m = lo
    for (int kc = 0; kc < kC; kc += 32) {
        #pragma unroll
        for (int i = 0; i < 4; i++) {
            int mrow = hi + i * 8;
            Ys[mrow][lo] = Yb[(size_t)(b * kM + m0 + mrow) * kC + kc + lo];
            Ws[mrow][lo] = Wm[(o0 + mrow) * kC + kc + lo];
        }
        __syncthreads();
        float yreg[32];
        #pragma unroll
        for (int c0 = 0; c0 < 32; c0 += 4) {
            float4 y4 = *reinterpret_cast<const float4*>(&Ys[lo][c0]);
            yreg[c0] = y4.x; yreg[c0 + 1] = y4.y; yreg[c0 + 2] = y4.z; yreg[c0 + 3] = y4.w;
        }
        #pragma unroll
        for (int i = 0; i < 4; i++) {
            int o = hi * 4 + i;
            float a = 0.f;
            #pragma unroll
            for (int c0 = 0; c0 < 32; c0 += 4) {
                float4 w4 = *reinterpret_cast<const float4*>(&Ws[o][c0]);
                a += yreg[c0] * w4.x + yreg[c0 + 1] * w4.y + yreg[c0 + 2] * w4.z + yreg[c0 + 3] * w4.w;
            }
            acc[i] += a;
        }
        __syncthreads();
    }
    #pragma unroll
    for (int i = 0; i < 4; i++)
        out[(size_t)(b * kC + o0 + hi * 4 + i) * kM + m0 + lo] = acc[i];
}

extern "C" void kernel_launch(void* const* d_in, const int* in_sizes, int n_in,
                              void* d_out, int out_size, void* d_ws, size_t ws_size,
                              hipStream_t stream) {
    const float* x     = (const float*)d_in[0];
    const float* gamma = (const float*)d_in[1];
    const float* beta  = (const float*)d_in[2];
    const float* rmean = (const float*)d_in[3];
    const float* rvar  = (const float*)d_in[4];
    const float* v_w   = (const float*)d_in[5];
    const float* z_w   = (const float*)d_in[6];
    const float* q_w   = (const float*)d_in[7];
    const float* o_w   = (const float*)d_in[8];
    float* out = (float*)d_out;

    char* wsb = (char*)d_ws;
    const size_t BMC = (size_t)kB * kM * kC;  // 1,179,648
    float* bninv   = (float*)wsb;            // bytes [0, 1024)
    float* bnshift = bninv + 256;            // bytes [1024, 2048)
    // WAS THE BUG: Zf at wsb+1024 BYTES overlapped bnshift -> z-conv clobbered
    // the BN shift before/while the q-conv read it. Start tensors at 4096.
    float* Zf = (float*)(wsb + 4096);
    float* Yf = Zf + BMC;
    __hip_bfloat16* Vb16 = (__hip_bfloat16*)(Yf + BMC);
    __hip_bfloat16* ZR16 = Vb16 + BMC;
    __hip_bfloat16* Qt16 = ZR16 + BMC;   // total ~16.5 MB

    prep_bn<<<dim3(1), dim3(256), 0, stream>>>(gamma, beta, rmean, rvar, bninv, bnshift);
    dim3 gconv(kM / 32, kC / 32, kB);
    conv_in<1><<<gconv, dim3(256), 0, stream>>>(x, v_w, bninv, bnshift, Vb16);
    conv_in<0><<<gconv, dim3(256), 0, stream>>>(x, z_w, bninv, bnshift, Zf);
    conv_in<2><<<gconv, dim3(256), 0, stream>>>(x, q_w, bninv, bnshift, Qt16);
    zr_kernel<<<dim3(kB * kM), dim3(256), 0, stream>>>(Zf, ZR16);
    flash_attn_mfma<<<dim3(kM / 32, kH, kB), dim3(64), 0, stream>>>(Vb16, ZR16, Qt16, Yf);
    conv_out<<<gconv, dim3(256), 0, stream>>>(Yf, o_w, out);
}

// Round 6
// 102.022 us; speedup vs baseline: 6.1413x; 1.4785x over previous
//
#include <hip/hip_runtime.h>
#include <hip/hip_bf16.h>
#include <math.h>

namespace {
constexpr int kC  = 256;   // channels
constexpr int kW  = 48;    // width
constexpr int kM  = 2304;  // tokens = 48*48
constexpr int kB  = 2;     // batch
constexpr int kDH = 32;    // head dim
constexpr int kH  = 8;     // heads
constexpr int kNS = 4;     // KV split chunks
constexpr int kNT = kM / 32;  // 72 m-tiles
}

typedef float  f32x4  __attribute__((ext_vector_type(4)));
typedef __bf16 bf16x8 __attribute__((ext_vector_type(8)));

// D = A*B + C, bf16 16x16x32.
// A: row=lane&15, k=(lane>>4)*8+j ; B: col=lane&15 ; D: col=lane&15, row=(lane>>4)*4+reg
__device__ __forceinline__ f32x4 mfma16(bf16x8 a, bf16x8 b, f32x4 c) {
    return __builtin_amdgcn_mfma_f32_16x16x32_bf16(a, b, c, 0, 0, 0);
}

// ---- BN scale/shift precompute -------------------------------------------
__global__ void prep_bn(const float* __restrict__ gamma, const float* __restrict__ beta,
                        const float* __restrict__ rmean, const float* __restrict__ rvar,
                        float* __restrict__ bninv, float* __restrict__ bnshift) {
    int c = threadIdx.x;
    float iv = gamma[c] / sqrtf(rvar[c] + 1e-5f);
    bninv[c] = iv;
    bnshift[c] = beta[c] - rmean[c] * iv;
}

// ---- pack the four 256x256 fp32 weights to bf16 (same row-major layout) --
__global__ __launch_bounds__(256) void pack_w(const float* __restrict__ w0, const float* __restrict__ w1,
                                              const float* __restrict__ w2, const float* __restrict__ w3,
                                              __hip_bfloat16* __restrict__ o0, __hip_bfloat16* __restrict__ o1,
                                              __hip_bfloat16* __restrict__ o2, __hip_bfloat16* __restrict__ o3) {
    const float* w = blockIdx.y == 0 ? w0 : blockIdx.y == 1 ? w1 : blockIdx.y == 2 ? w2 : w3;
    __hip_bfloat16* o = blockIdx.y == 0 ? o0 : blockIdx.y == 1 ? o1 : blockIdx.y == 2 ? o2 : o3;
    int idx = (blockIdx.x * 256 + threadIdx.x) * 4;
    float4 v = *reinterpret_cast<const float4*>(w + idx);
    o[idx]     = __float2bfloat16(v.x);
    o[idx + 1] = __float2bfloat16(v.y);
    o[idx + 2] = __float2bfloat16(v.z);
    o[idx + 3] = __float2bfloat16(v.w);
}

// ---- xn^T: (B,C,M) fp32 + BN -> (B,M,C) bf16 ------------------------------
__global__ __launch_bounds__(256) void xnt_kernel(const float* __restrict__ x,
                                                  const float* __restrict__ bninv,
                                                  const float* __restrict__ bnshift,
                                                  __hip_bfloat16* __restrict__ Xnt) {
    __shared__ float T[64][65];
    int t = threadIdx.x;
    int m0 = blockIdx.x * 64, c0 = blockIdx.y * 64, b = blockIdx.z;
    int ml = t & 63;
    #pragma unroll
    for (int i = 0; i < 16; i++) {
        int c = (t >> 6) + i * 4;
        T[c][ml] = x[(size_t)(b * kC + c0 + c) * kM + m0 + ml] * bninv[c0 + c] + bnshift[c0 + c];
    }
    __syncthreads();
    int mr = t >> 2, cseg = (t & 3) * 16;
    __hip_bfloat16 v[16];
    #pragma unroll
    for (int j = 0; j < 16; j++) v[j] = __float2bfloat16(T[cseg + j][mr]);
    __hip_bfloat16* dst = Xnt + (size_t)(b * kM + m0 + mr) * kC + c0 + cseg;
    *reinterpret_cast<bf16x8*>(dst)     = *reinterpret_cast<bf16x8*>(&v[0]);
    *reinterpret_cast<bf16x8*>(dst + 8) = *reinterpret_cast<bf16x8*>(&v[8]);
}

// ---- fused-BN 1x1 convs as bf16 MFMA GEMM: 1 wave = 16m x 64o, one matrix -
// A = Xnt rows (m), B = W rows (o). D: col(lane&15)=o, row(4g+r)=m.
// mat 0: V bf16 (B,M,C) * 1/sqrt(32) ; mat 1: Z bf16 (B,M,C) ; mat 2: Qt bf16 (B,h,dh,M)
__global__ __launch_bounds__(64) void conv_gemm(const __hip_bfloat16* __restrict__ Xnt,
                                                const __hip_bfloat16* __restrict__ Wv,
                                                const __hip_bfloat16* __restrict__ Wz,
                                                const __hip_bfloat16* __restrict__ Wq,
                                                __hip_bfloat16* __restrict__ V16,
                                                __hip_bfloat16* __restrict__ Zb16,
                                                __hip_bfloat16* __restrict__ Qt16) {
    int t = threadIdx.x, li = t & 15, g = t >> 4;
    int m0 = blockIdx.x * 16, o0 = blockIdx.y * 64;
    int mat = blockIdx.z >> 1, b = blockIdx.z & 1;
    const __hip_bfloat16* W = mat == 0 ? Wv : mat == 1 ? Wz : Wq;

    bf16x8 a[8];
    const __hip_bfloat16* ap = Xnt + (size_t)(b * kM + m0 + li) * kC + g * 8;
    #pragma unroll
    for (int kb = 0; kb < 8; kb++) a[kb] = *reinterpret_cast<const bf16x8*>(ap + kb * 32);

    f32x4 acc[4] = {{0,0,0,0},{0,0,0,0},{0,0,0,0},{0,0,0,0}};
    const __hip_bfloat16* wp = W + g * 8;
    #pragma unroll
    for (int kb = 0; kb < 8; kb++) {
        #pragma unroll
        for (int ot = 0; ot < 4; ot++) {
            bf16x8 bw = *reinterpret_cast<const bf16x8*>(wp + (size_t)(o0 + ot * 16 + li) * kC + kb * 32);
            acc[ot] = mfma16(a[kb], bw, acc[ot]);
        }
    }

    int m = m0 + 4 * g;
    if (mat == 0) {
        const float SCALE = 0.17677669529663687f;  // 1/sqrt(32)
        #pragma unroll
        for (int ot = 0; ot < 4; ot++)
            #pragma unroll
            for (int r = 0; r < 4; r++)
                V16[(size_t)(b * kM + m + r) * kC + o0 + ot * 16 + li] = __float2bfloat16(acc[ot][r] * SCALE);
    } else if (mat == 1) {
        #pragma unroll
        for (int ot = 0; ot < 4; ot++)
            #pragma unroll
            for (int r = 0; r < 4; r++)
                Zb16[(size_t)(b * kM + m + r) * kC + o0 + ot * 16 + li] = __float2bfloat16(acc[ot][r]);
    } else {
        #pragma unroll
        for (int ot = 0; ot < 4; ot++) {
            int o = o0 + ot * 16 + li, hh = o >> 5, d = o & 31;
            __hip_bfloat16* base = Qt16 + ((size_t)(b * kH + hh) * kDH + d) * kM + m;
            *reinterpret_cast<__hip_bfloat162*>(base) =
                __float22bfloat162_rn(make_float2(acc[ot][0], acc[ot][1]));
            *reinterpret_cast<__hip_bfloat162*>(base + 2) =
                __float22bfloat162_rn(make_float2(acc[ot][2], acc[ot][3]));
        }
    }
}

// ---- zr = l2n(z) + l2n(r): bf16 in, bf16 out (B,M,C) ---------------------
__global__ __launch_bounds__(256) void zr_kernel(const __hip_bfloat16* __restrict__ Z,
                                                 __hip_bfloat16* __restrict__ ZRo) {
    int bm = blockIdx.x;            // b*M + m
    int c = threadIdx.x;            // 0..255
    int m = bm % kM;
    float zv = __bfloat162float(Z[(size_t)bm * kC + c]);
    float ss = zv * zv;
    #pragma unroll
    for (int k = 32; k >= 1; k >>= 1) ss += __shfl_xor(ss, k);
    __shared__ float part[4];
    if ((c & 63) == 0) part[c >> 6] = ss;
    __syncthreads();
    float tot = part[0] + part[1] + part[2] + part[3];
    float zinv = 1.0f / sqrtf(tot + 1e-6f);
    int yrow = m / kW, xcol = m % kW;
    int cc  = (c < 128) ? c : (c - 128);
    int pos = (c < 128) ? xcol : yrow;
    float dv = __expf((float)(cc & ~1) * (float)(-9.210340371976184 / 128.0));
    float pd = (float)pos * dv;
    float rv = (c & 1) ? cosf(pd) : sinf(pd);
    const float RINV = 1.0f / sqrtf(128.0f + 1e-6f);
    ZRo[(size_t)bm * kC + c] = __float2bfloat16(zv * zinv + rv * RINV);
}

// ---- KV-split MFMA flash attention: 1 wave per (32 q-rows, head, b, chunk)
// Writes raw (unnormalized) partial Y^T + per-row (m, l) for the combine pass.
__global__ __launch_bounds__(64) void flash_attn_split(
    const __hip_bfloat16* __restrict__ V,    // (B,M,C) bf16, pre-scaled by 1/sqrt(32)
    const __hip_bfloat16* __restrict__ ZR,   // (B,M,C) bf16
    const __hip_bfloat16* __restrict__ Qt,   // (B,h,dh,M) bf16
    float* __restrict__ Yp,                  // [NS][B][H][NT][32 rows][32 dh]
    float* __restrict__ ML)                  // [NS][B][H][NT][32 rows][2]
{
    __shared__ __hip_bfloat16 P_lds[32][72];
    const int t = threadIdx.x;
    const int li = t & 15, g = t >> 4;
    const int mtile = blockIdx.x;
    const int m0 = mtile * 32;
    const int h = blockIdx.y;
    const int b = blockIdx.z & 1, s = blockIdx.z >> 1;
    const int nBeg = s * (kM / kNS), nEnd = nBeg + (kM / kNS);

    const f32x4 zero4 = {0.f, 0.f, 0.f, 0.f};

    bf16x8 vfrag[2];
    #pragma unroll
    for (int mt = 0; mt < 2; mt++)
        vfrag[mt] = *reinterpret_cast<const bf16x8*>(
            V + ((size_t)(b * kM + m0 + mt * 16 + li) * kC + h * kDH + g * 8));

    const __hip_bfloat16* zrp = ZR + ((size_t)b * kM * kC + h * kDH + g * 8);
    const __hip_bfloat16* qtp = Qt + ((size_t)(b * kH + h) * kDH) * (size_t)kM + g * 8;

    f32x4 acc[2][2];
    #pragma unroll
    for (int mt = 0; mt < 2; mt++)
        #pragma unroll
        for (int dt = 0; dt < 2; dt++) acc[mt][dt] = zero4;
    float mval[2] = {-INFINITY, -INFINITY};
    float lsum[2] = {0.f, 0.f};

    bf16x8 za[4], qa[2][2];
    #pragma unroll
    for (int tl = 0; tl < 4; tl++)
        za[tl] = *reinterpret_cast<const bf16x8*>(zrp + (size_t)(nBeg + tl * 16 + li) * kC);
    #pragma unroll
    for (int dt = 0; dt < 2; dt++)
        #pragma unroll
        for (int kc = 0; kc < 2; kc++)
            qa[dt][kc] = *reinterpret_cast<const bf16x8*>(qtp + (size_t)(dt * 16 + li) * kM + nBeg + kc * 32);

    for (int n0 = nBeg; n0 < nEnd; n0 += 64) {
        f32x4 st[2][4];
        #pragma unroll
        for (int mt = 0; mt < 2; mt++)
            #pragma unroll
            for (int tl = 0; tl < 4; tl++)
                st[mt][tl] = mfma16(za[tl], vfrag[mt], zero4);

        const int n1 = (n0 + 64 < nEnd) ? (n0 + 64) : nBeg;
        bf16x8 zn[4], qn[2][2];
        #pragma unroll
        for (int tl = 0; tl < 4; tl++)
            zn[tl] = *reinterpret_cast<const bf16x8*>(zrp + (size_t)(n1 + tl * 16 + li) * kC);
        #pragma unroll
        for (int dt = 0; dt < 2; dt++)
            #pragma unroll
            for (int kc = 0; kc < 2; kc++)
                qn[dt][kc] = *reinterpret_cast<const bf16x8*>(qtp + (size_t)(dt * 16 + li) * kM + n1 + kc * 32);

        #pragma unroll
        for (int mt = 0; mt < 2; mt++) {
            float rmax = st[mt][0][0];
            #pragma unroll
            for (int tl = 0; tl < 4; tl++)
                #pragma unroll
                for (int r = 0; r < 4; r++) rmax = fmaxf(rmax, st[mt][tl][r]);
            rmax = fmaxf(rmax, __shfl_xor(rmax, 16));
            rmax = fmaxf(rmax, __shfl_xor(rmax, 32));
            float nm = fmaxf(mval[mt], rmax);
            float resc = __expf(mval[mt] - nm);
            mval[mt] = nm;
            float p[4][4];
            float rsum = 0.f;
            #pragma unroll
            for (int tl = 0; tl < 4; tl++)
                #pragma unroll
                for (int r = 0; r < 4; r++) {
                    p[tl][r] = __expf(st[mt][tl][r] - nm);
                    rsum += p[tl][r];
                }
            rsum += __shfl_xor(rsum, 16);
            rsum += __shfl_xor(rsum, 32);
            lsum[mt] = lsum[mt] * resc + rsum;
            #pragma unroll
            for (int dt = 0; dt < 2; dt++) acc[mt][dt] = acc[mt][dt] * resc;
            #pragma unroll
            for (int tl = 0; tl < 4; tl++)
                #pragma unroll
                for (int pr = 0; pr < 2; pr++) {
                    __hip_bfloat162 h2 = __float22bfloat162_rn(
                        make_float2(p[tl][2 * pr], p[tl][2 * pr + 1]));
                    *reinterpret_cast<__hip_bfloat162*>(
                        &P_lds[mt * 16 + li][tl * 16 + 4 * g + 2 * pr]) = h2;
                }
        }

        __syncthreads();   // RAW: cross-lane P visible before reads

        #pragma unroll
        for (int mt = 0; mt < 2; mt++)
            #pragma unroll
            for (int kc = 0; kc < 2; kc++) {
                bf16x8 pb = *reinterpret_cast<const bf16x8*>(&P_lds[mt * 16 + li][kc * 32 + g * 8]);
                #pragma unroll
                for (int dt = 0; dt < 2; dt++)
                    acc[mt][dt] = mfma16(qa[dt][kc], pb, acc[mt][dt]);
            }

        __syncthreads();   // WAR: next P writes can't hoist above reads

        #pragma unroll
        for (int tl = 0; tl < 4; tl++) za[tl] = zn[tl];
        #pragma unroll
        for (int dt = 0; dt < 2; dt++)
            #pragma unroll
            for (int kc = 0; kc < 2; kc++) qa[dt][kc] = qn[dt][kc];
    }

    const int pt = ((s * kB + b) * kH + h) * kNT + mtile;
    float* yp = Yp + (size_t)pt * 1024;
    #pragma unroll
    for (int mt = 0; mt < 2; mt++)
        #pragma unroll
        for (int dt = 0; dt < 2; dt++)
            #pragma unroll
            for (int r = 0; r < 4; r++)
                yp[(mt * 16 + li) * 32 + dt * 16 + 4 * g + r] = acc[mt][dt][r];
    if (g == 0) {
        #pragma unroll
        for (int mt = 0; mt < 2; mt++) {
            ML[((size_t)pt * 32 + mt * 16 + li) * 2 + 0] = mval[mt];
            ML[((size_t)pt * 32 + mt * 16 + li) * 2 + 1] = lsum[mt];
        }
    }
}

// ---- combine KV-split partials -> Y bf16 (B,M,C) --------------------------
__global__ __launch_bounds__(64) void attn_combine(const float* __restrict__ Yp,
                                                   const float* __restrict__ ML,
                                                   __hip_bfloat16* __restrict__ Y16) {
    int mtile = blockIdx.x, h = blockIdx.y, b = blockIdx.z;
    int t = threadIdx.x;
    int row = t & 31, dp = (t >> 5) * 16;
    float mv[kNS], lv[kNS];
    #pragma unroll
    for (int s = 0; s < kNS; s++) {
        size_t pt = ((size_t)(s * kB + b) * kH + h) * kNT + mtile;
        mv[s] = ML[(pt * 32 + row) * 2 + 0];
        lv[s] = ML[(pt * 32 + row) * 2 + 1];
    }
    float M = mv[0];
    #pragma unroll
    for (int s = 1; s < kNS; s++) M = fmaxf(M, mv[s]);
    float L = 0.f, w[kNS];
    #pragma unroll
    for (int s = 0; s < kNS; s++) { w[s] = __expf(mv[s] - M); L += lv[s] * w[s]; }
    float inv = 1.0f / L;
    float o[16] = {0.f};
    #pragma unroll
    for (int s = 0; s < kNS; s++) {
        const float* yp = Yp + (((size_t)(s * kB + b) * kH + h) * kNT + mtile) * 1024 + row * 32 + dp;
        #pragma unroll
        for (int j = 0; j < 4; j++) {
            float4 v = *reinterpret_cast<const float4*>(yp + j * 4);
            o[j * 4 + 0] += v.x * w[s];
            o[j * 4 + 1] += v.y * w[s];
            o[j * 4 + 2] += v.z * w[s];
            o[j * 4 + 3] += v.w * w[s];
        }
    }
    __hip_bfloat16* dst = Y16 + (size_t)(b * kM + mtile * 32 + row) * kC + h * kDH + dp;
    __hip_bfloat16 vb[16];
    #pragma unroll
    for (int j = 0; j < 16; j++) vb[j] = __float2bfloat16(o[j] * inv);
    *reinterpret_cast<bf16x8*>(dst)     = *reinterpret_cast<bf16x8*>(&vb[0]);
    *reinterpret_cast<bf16x8*>(dst + 8) = *reinterpret_cast<bf16x8*>(&vb[8]);
}

// ---- output conv as bf16 MFMA GEMM: 1 wave = 16m x 32o --------------------
// out[b][o][m] = sum_c Wo[o][c] * Y16[b][m][c]; D col=o(li), rows=m(4g+r) -> f32x4 store
__global__ __launch_bounds__(64) void conv_out_gemm(const __hip_bfloat16* __restrict__ Y16,
                                                    const __hip_bfloat16* __restrict__ Wo,
                                                    float* __restrict__ out) {
    int t = threadIdx.x, li = t & 15, g = t >> 4;
    int m0 = blockIdx.x * 16, o0 = blockIdx.y * 32, b = blockIdx.z;

    bf16x8 a[8];
    const __hip_bfloat16* ap = Y16 + (size_t)(b * kM + m0 + li) * kC + g * 8;
    #pragma unroll
    for (int kb = 0; kb < 8; kb++) a[kb] = *reinterpret_cast<const bf16x8*>(ap + kb * 32);

    f32x4 acc[2] = {{0,0,0,0},{0,0,0,0}};
    const __hip_bfloat16* wp = Wo + g * 8;
    #pragma unroll
    for (int kb = 0; kb < 8; kb++) {
        #pragma unroll
        for (int ot = 0; ot < 2; ot++) {
            bf16x8 bw = *reinterpret_cast<const bf16x8*>(wp + (size_t)(o0 + ot * 16 + li) * kC + kb * 32);
            acc[ot] = mfma16(a[kb], bw, acc[ot]);
        }
    }
    #pragma unroll
    for (int ot = 0; ot < 2; ot++) {
        int o = o0 + ot * 16 + li;
        *reinterpret_cast<f32x4*>(out + (size_t)(b * kC + o) * kM + m0 + 4 * g) = acc[ot];
    }
}

extern "C" void kernel_launch(void* const* d_in, const int* in_sizes, int n_in,
                              void* d_out, int out_size, void* d_ws, size_t ws_size,
                              hipStream_t stream) {
    const float* x     = (const float*)d_in[0];
    const float* gamma = (const float*)d_in[1];
    const float* beta  = (const float*)d_in[2];
    const float* rmean = (const float*)d_in[3];
    const float* rvar  = (const float*)d_in[4];
    const float* v_w   = (const float*)d_in[5];
    const float* z_w   = (const float*)d_in[6];
    const float* q_w   = (const float*)d_in[7];
    const float* o_w   = (const float*)d_in[8];
    float* out = (float*)d_out;

    char* wsb = (char*)d_ws;
    const size_t BMC = (size_t)kB * kM * kC;  // 1,179,648
    float* bninv   = (float*)wsb;             // [0, 1024)
    float* bnshift = bninv + 256;             // [1024, 2048)
    __hip_bfloat16* Wv16 = (__hip_bfloat16*)(wsb + 4096);
    __hip_bfloat16* Wz16 = Wv16 + 65536;
    __hip_bfloat16* Wq16 = Wz16 + 65536;
    __hip_bfloat16* Wo16 = Wq16 + 65536;
    __hip_bfloat16* Xnt  = Wo16 + 65536;
    __hip_bfloat16* V16  = Xnt + BMC;
    __hip_bfloat16* Zb16 = V16 + BMC;
    __hip_bfloat16* ZR16 = Zb16 + BMC;
    __hip_bfloat16* Qt16 = ZR16 + BMC;
    __hip_bfloat16* Y16  = Qt16 + BMC;
    float* Yp = (float*)(Y16 + BMC);                       // kNS*kB*kH*kNT*1024 f32
    float* MLb = Yp + (size_t)kNS * kB * kH * kNT * 1024;  // kNS*kB*kH*kNT*64 f32
    // total ~34.8 MB

    prep_bn<<<dim3(1), dim3(256), 0, stream>>>(gamma, beta, rmean, rvar, bninv, bnshift);
    pack_w<<<dim3(64, 4), dim3(256), 0, stream>>>(v_w, z_w, q_w, o_w, Wv16, Wz16, Wq16, Wo16);
    xnt_kernel<<<dim3(kM / 64, kC / 64, kB), dim3(256), 0, stream>>>(x, bninv, bnshift, Xnt);
    conv_gemm<<<dim3(kM / 16, kC / 64, 3 * kB), dim3(64), 0, stream>>>(
        Xnt, Wv16, Wz16, Wq16, V16, Zb16, Qt16);
    zr_kernel<<<dim3(kB * kM), dim3(256), 0, stream>>>(Zb16, ZR16);
    flash_attn_split<<<dim3(kNT, kH, kB * kNS), dim3(64), 0, stream>>>(V16, ZR16, Qt16, Yp, MLb);
    attn_combine<<<dim3(kNT, kH, kB), dim3(64), 0, stream>>>(Yp, MLb, Y16);
    conv_out_gemm<<<dim3(kM / 16, kC / 32, kB), dim3(64), 0, stream>>>(Y16, Wo16, out);
}

// Round 7
// 93.710 us; speedup vs baseline: 6.6860x; 1.0887x over previous
//
#include <hip/hip_runtime.h>
#include <hip/hip_bf16.h>
#include <math.h>

namespace {
constexpr int kC  = 256;   // channels
constexpr int kW  = 48;    // width
constexpr int kM  = 2304;  // tokens = 48*48
constexpr int kB  = 2;     // batch
constexpr int kDH = 32;    // head dim
constexpr int kH  = 8;     // heads
constexpr int kNT = kM / 32;  // 72 m-tiles
}

typedef float  f32x4  __attribute__((ext_vector_type(4)));
typedef __bf16 bf16x8 __attribute__((ext_vector_type(8)));

// D = A*B + C, bf16 16x16x32.
// A: row=lane&15, k=(lane>>4)*8+j ; B: col=lane&15 ; D: col=lane&15, row=(lane>>4)*4+reg
__device__ __forceinline__ f32x4 mfma16(bf16x8 a, bf16x8 b, f32x4 c) {
    return __builtin_amdgcn_mfma_f32_16x16x32_bf16(a, b, c, 0, 0, 0);
}

// ---- BN scale/shift precompute -------------------------------------------
__global__ void prep_bn(const float* __restrict__ gamma, const float* __restrict__ beta,
                        const float* __restrict__ rmean, const float* __restrict__ rvar,
                        float* __restrict__ bninv, float* __restrict__ bnshift) {
    int c = threadIdx.x;
    float iv = gamma[c] / sqrtf(rvar[c] + 1e-5f);
    bninv[c] = iv;
    bnshift[c] = beta[c] - rmean[c] * iv;
}

// ---- pack the four 256x256 fp32 weights to bf16 (same row-major layout) --
__global__ __launch_bounds__(256) void pack_w(const float* __restrict__ w0, const float* __restrict__ w1,
                                              const float* __restrict__ w2, const float* __restrict__ w3,
                                              __hip_bfloat16* __restrict__ o0, __hip_bfloat16* __restrict__ o1,
                                              __hip_bfloat16* __restrict__ o2, __hip_bfloat16* __restrict__ o3) {
    const float* w = blockIdx.y == 0 ? w0 : blockIdx.y == 1 ? w1 : blockIdx.y == 2 ? w2 : w3;
    __hip_bfloat16* o = blockIdx.y == 0 ? o0 : blockIdx.y == 1 ? o1 : blockIdx.y == 2 ? o2 : o3;
    int idx = (blockIdx.x * 256 + threadIdx.x) * 4;
    float4 v = *reinterpret_cast<const float4*>(w + idx);
    o[idx]     = __float2bfloat16(v.x);
    o[idx + 1] = __float2bfloat16(v.y);
    o[idx + 2] = __float2bfloat16(v.z);
    o[idx + 3] = __float2bfloat16(v.w);
}

// ---- xn^T: (B,C,M) fp32 + BN -> (B,M,C) bf16 ------------------------------
__global__ __launch_bounds__(256) void xnt_kernel(const float* __restrict__ x,
                                                  const float* __restrict__ bninv,
                                                  const float* __restrict__ bnshift,
                                                  __hip_bfloat16* __restrict__ Xnt) {
    __shared__ float T[64][65];
    int t = threadIdx.x;
    int m0 = blockIdx.x * 64, c0 = blockIdx.y * 64, b = blockIdx.z;
    int ml = t & 63;
    #pragma unroll
    for (int i = 0; i < 16; i++) {
        int c = (t >> 6) + i * 4;
        T[c][ml] = x[(size_t)(b * kC + c0 + c) * kM + m0 + ml] * bninv[c0 + c] + bnshift[c0 + c];
    }
    __syncthreads();
    int mr = t >> 2, cseg = (t & 3) * 16;
    __hip_bfloat16 v[16];
    #pragma unroll
    for (int j = 0; j < 16; j++) v[j] = __float2bfloat16(T[cseg + j][mr]);
    __hip_bfloat16* dst = Xnt + (size_t)(b * kM + m0 + mr) * kC + c0 + cseg;
    *reinterpret_cast<bf16x8*>(dst)     = *reinterpret_cast<bf16x8*>(&v[0]);
    *reinterpret_cast<bf16x8*>(dst + 8) = *reinterpret_cast<bf16x8*>(&v[8]);
}

// ---- fused-BN 1x1 convs as bf16 MFMA GEMM: 1 wave = 16m x 64o, one matrix -
__global__ __launch_bounds__(64) void conv_gemm(const __hip_bfloat16* __restrict__ Xnt,
                                                const __hip_bfloat16* __restrict__ Wv,
                                                const __hip_bfloat16* __restrict__ Wz,
                                                const __hip_bfloat16* __restrict__ Wq,
                                                __hip_bfloat16* __restrict__ V16,
                                                __hip_bfloat16* __restrict__ Zb16,
                                                __hip_bfloat16* __restrict__ Qt16) {
    int t = threadIdx.x, li = t & 15, g = t >> 4;
    int m0 = blockIdx.x * 16, o0 = blockIdx.y * 64;
    int mat = blockIdx.z >> 1, b = blockIdx.z & 1;
    const __hip_bfloat16* W = mat == 0 ? Wv : mat == 1 ? Wz : Wq;

    bf16x8 a[8];
    const __hip_bfloat16* ap = Xnt + (size_t)(b * kM + m0 + li) * kC + g * 8;
    #pragma unroll
    for (int kb = 0; kb < 8; kb++) a[kb] = *reinterpret_cast<const bf16x8*>(ap + kb * 32);

    f32x4 acc[4] = {{0,0,0,0},{0,0,0,0},{0,0,0,0},{0,0,0,0}};
    const __hip_bfloat16* wp = W + g * 8;
    #pragma unroll
    for (int kb = 0; kb < 8; kb++) {
        #pragma unroll
        for (int ot = 0; ot < 4; ot++) {
            bf16x8 bw = *reinterpret_cast<const bf16x8*>(wp + (size_t)(o0 + ot * 16 + li) * kC + kb * 32);
            acc[ot] = mfma16(a[kb], bw, acc[ot]);
        }
    }

    int m = m0 + 4 * g;
    if (mat == 0) {
        const float SCALE = 0.17677669529663687f;  // 1/sqrt(32)
        #pragma unroll
        for (int ot = 0; ot < 4; ot++)
            #pragma unroll
            for (int r = 0; r < 4; r++)
                V16[(size_t)(b * kM + m + r) * kC + o0 + ot * 16 + li] = __float2bfloat16(acc[ot][r] * SCALE);
    } else if (mat == 1) {
        #pragma unroll
        for (int ot = 0; ot < 4; ot++)
            #pragma unroll
            for (int r = 0; r < 4; r++)
                Zb16[(size_t)(b * kM + m + r) * kC + o0 + ot * 16 + li] = __float2bfloat16(acc[ot][r]);
    } else {
        #pragma unroll
        for (int ot = 0; ot < 4; ot++) {
            int o = o0 + ot * 16 + li, hh = o >> 5, d = o & 31;
            __hip_bfloat16* base = Qt16 + ((size_t)(b * kH + hh) * kDH + d) * kM + m;
            *reinterpret_cast<__hip_bfloat162*>(base) =
                __float22bfloat162_rn(make_float2(acc[ot][0], acc[ot][1]));
            *reinterpret_cast<__hip_bfloat162*>(base + 2) =
                __float22bfloat162_rn(make_float2(acc[ot][2], acc[ot][3]));
        }
    }
}

// ---- zr = l2n(z) + l2n(r): bf16 in, bf16 out (B,M,C) ---------------------
__global__ __launch_bounds__(256) void zr_kernel(const __hip_bfloat16* __restrict__ Z,
                                                 __hip_bfloat16* __restrict__ ZRo) {
    int bm = blockIdx.x;
    int c = threadIdx.x;
    int m = bm % kM;
    float zv = __bfloat162float(Z[(size_t)bm * kC + c]);
    float ss = zv * zv;
    #pragma unroll
    for (int k = 32; k >= 1; k >>= 1) ss += __shfl_xor(ss, k);
    __shared__ float part[4];
    if ((c & 63) == 0) part[c >> 6] = ss;
    __syncthreads();
    float tot = part[0] + part[1] + part[2] + part[3];
    float zinv = 1.0f / sqrtf(tot + 1e-6f);
    int yrow = m / kW, xcol = m % kW;
    int cc  = (c < 128) ? c : (c - 128);
    int pos = (c < 128) ? xcol : yrow;
    float dv = __expf((float)(cc & ~1) * (float)(-9.210340371976184 / 128.0));
    float pd = (float)pos * dv;
    float rv = (c & 1) ? cosf(pd) : sinf(pd);
    const float RINV = 1.0f / sqrtf(128.0f + 1e-6f);
    ZRo[(size_t)bm * kC + c] = __float2bfloat16(zv * zinv + rv * RINV);
}

// ---- fused flash attention: 4 waves/block, wave w owns KV chunk w --------
// No max-tracking (|logit| <~ 23 by norm bound; exp fp32-safe, clamped at 60).
// No barriers in the KV loop: per-wave P region, asm lgkmcnt ordering.
// End: LDS combine of 4 wave-partials (acc, lsum) -> Y16 bf16.
__global__ __launch_bounds__(256) void flash_attn_fused(
    const __hip_bfloat16* __restrict__ V,    // (B,M,C) bf16, pre-scaled by 1/sqrt(32)
    const __hip_bfloat16* __restrict__ ZR,   // (B,M,C) bf16
    const __hip_bfloat16* __restrict__ Qt,   // (B,h,dh,M) bf16
    __hip_bfloat16* __restrict__ Y16)        // (B,M,C) bf16
{
    // [0,18432): per-wave 4608B = P[32][72] bf16 during loop, then Aw[32][36] f32
    // [18432,20480): Ls[w][mt][li][g] f32
    __shared__ char smem[20480];
    const int t = threadIdx.x;
    const int w = t >> 6;
    const int lane = t & 63;
    const int li = lane & 15, g = lane >> 4;
    const int m0 = blockIdx.x * 32;
    const int h = blockIdx.y, b = blockIdx.z;
    const f32x4 zero4 = {0.f, 0.f, 0.f, 0.f};

    __hip_bfloat16* Pw = (__hip_bfloat16*)(smem + w * 4608);  // row pitch 72

    bf16x8 vfrag[2];
    #pragma unroll
    for (int mt = 0; mt < 2; mt++)
        vfrag[mt] = *reinterpret_cast<const bf16x8*>(
            V + ((size_t)(b * kM + m0 + mt * 16 + li) * kC + h * kDH + g * 8));

    const __hip_bfloat16* zrp = ZR + ((size_t)b * kM * kC + h * kDH + g * 8);
    const __hip_bfloat16* qtp = Qt + ((size_t)(b * kH + h) * kDH) * (size_t)kM + g * 8;

    const int nBeg = w * (kM / 4);   // 576-col chunk, 9 iters of 64
    f32x4 acc[2][2] = {{zero4, zero4}, {zero4, zero4}};
    float lsum[2] = {0.f, 0.f};

    bf16x8 za[4], qa[2][2];
    #pragma unroll
    for (int tl = 0; tl < 4; tl++)
        za[tl] = *reinterpret_cast<const bf16x8*>(zrp + (size_t)(nBeg + tl * 16 + li) * kC);
    #pragma unroll
    for (int dt = 0; dt < 2; dt++)
        #pragma unroll
        for (int kc = 0; kc < 2; kc++)
            qa[dt][kc] = *reinterpret_cast<const bf16x8*>(qtp + (size_t)(dt * 16 + li) * kM + nBeg + kc * 32);

    for (int it = 0; it < 9; ++it) {
        const int n0 = nBeg + it * 64;
        const int n1 = (it < 8) ? (n0 + 64) : nBeg;   // wrap harmlessly on last

        // S^T: st[mt][tl] col m = mt*16+li, row n = tl*16+4g+r
        f32x4 st[2][4];
        #pragma unroll
        for (int mt = 0; mt < 2; mt++)
            #pragma unroll
            for (int tl = 0; tl < 4; tl++)
                st[mt][tl] = mfma16(za[tl], vfrag[mt], zero4);

        // prefetch next ZR tile into the same regs (issued now, used next iter)
        #pragma unroll
        for (int tl = 0; tl < 4; tl++)
            za[tl] = *reinterpret_cast<const bf16x8*>(zrp + (size_t)(n1 + tl * 16 + li) * kC);

        // softmax-lite: raw exp, thread-local partial sums, pack to LDS (b64)
        #pragma unroll
        for (int mt = 0; mt < 2; mt++) {
            float rs = 0.f;
            #pragma unroll
            for (int tl = 0; tl < 4; tl++) {
                float p0 = __expf(fminf(st[mt][tl][0], 60.f));
                float p1 = __expf(fminf(st[mt][tl][1], 60.f));
                float p2 = __expf(fminf(st[mt][tl][2], 60.f));
                float p3 = __expf(fminf(st[mt][tl][3], 60.f));
                rs += (p0 + p1) + (p2 + p3);
                union { uint2 u2; __hip_bfloat162 h2[2]; } pk;
                pk.h2[0] = __float22bfloat162_rn(make_float2(p0, p1));
                pk.h2[1] = __float22bfloat162_rn(make_float2(p2, p3));
                *reinterpret_cast<uint2*>(&Pw[(mt * 16 + li) * 72 + tl * 16 + 4 * g]) = pk.u2;
            }
            lsum[mt] += rs;
        }

        // RAW: all lanes' P writes complete before cross-lane reads
        asm volatile("s_waitcnt lgkmcnt(0)" ::: "memory");
        __builtin_amdgcn_sched_barrier(0);

        #pragma unroll
        for (int mt = 0; mt < 2; mt++)
            #pragma unroll
            for (int kc = 0; kc < 2; kc++) {
                bf16x8 pb = *reinterpret_cast<const bf16x8*>(&Pw[(mt * 16 + li) * 72 + kc * 32 + g * 8]);
                #pragma unroll
                for (int dt = 0; dt < 2; dt++)
                    acc[mt][dt] = mfma16(qa[dt][kc], pb, acc[mt][dt]);
            }

        // WAR: drain reads before next iter's writes (+ compile-time fence)
        asm volatile("s_waitcnt lgkmcnt(0)" ::: "memory");
        __builtin_amdgcn_sched_barrier(0);

        // prefetch next Q tile (issued now, used next iter's PV)
        #pragma unroll
        for (int dt = 0; dt < 2; dt++)
            #pragma unroll
            for (int kc = 0; kc < 2; kc++)
                qa[dt][kc] = *reinterpret_cast<const bf16x8*>(qtp + (size_t)(dt * 16 + li) * kM + n1 + kc * 32);
    }

    // stage this wave's partials over its own (dead) P region
    float* Aw = (float*)(smem + w * 4608);    // [32][36] pitch 36
    #pragma unroll
    for (int mt = 0; mt < 2; mt++)
        #pragma unroll
        for (int dt = 0; dt < 2; dt++)
            *reinterpret_cast<f32x4*>(&Aw[(mt * 16 + li) * 36 + dt * 16 + 4 * g]) = acc[mt][dt];
    float* Ls = (float*)(smem + 18432);
    #pragma unroll
    for (int mt = 0; mt < 2; mt++)
        Ls[((w * 2 + mt) * 16 + li) * 4 + g] = lsum[mt];
    __syncthreads();

    // combine: thread t -> row = t&31, d0 = (t>>5)*4
    const int row = t & 31, d0 = (t >> 5) * 4;
    const int mt2 = row >> 4, li2 = row & 15;
    float L = 0.f;
    #pragma unroll
    for (int w2 = 0; w2 < 4; w2++) {
        f32x4 l4 = *reinterpret_cast<const f32x4*>(&Ls[((w2 * 2 + mt2) * 16 + li2) * 4]);
        L += (l4[0] + l4[1]) + (l4[2] + l4[3]);
    }
    f32x4 s4 = zero4;
    #pragma unroll
    for (int w2 = 0; w2 < 4; w2++) {
        const float* aw = (const float*)(smem + w2 * 4608);
        f32x4 a4 = *reinterpret_cast<const f32x4*>(&aw[row * 36 + d0]);
        s4 = s4 + a4;
    }
    float inv = 1.0f / L;
    union { uint2 u2; __hip_bfloat162 h2[2]; } o;
    o.h2[0] = __float22bfloat162_rn(make_float2(s4[0] * inv, s4[1] * inv));
    o.h2[1] = __float22bfloat162_rn(make_float2(s4[2] * inv, s4[3] * inv));
    *reinterpret_cast<uint2*>(Y16 + (size_t)(b * kM + m0 + row) * kC + h * kDH + d0) = o.u2;
}

// ---- output conv as bf16 MFMA GEMM: 1 wave = 16m x 32o --------------------
__global__ __launch_bounds__(64) void conv_out_gemm(const __hip_bfloat16* __restrict__ Y16,
                                                    const __hip_bfloat16* __restrict__ Wo,
                                                    float* __restrict__ out) {
    int t = threadIdx.x, li = t & 15, g = t >> 4;
    int m0 = blockIdx.x * 16, o0 = blockIdx.y * 32, b = blockIdx.z;

    bf16x8 a[8];
    const __hip_bfloat16* ap = Y16 + (size_t)(b * kM + m0 + li) * kC + g * 8;
    #pragma unroll
    for (int kb = 0; kb < 8; kb++) a[kb] = *reinterpret_cast<const bf16x8*>(ap + kb * 32);

    f32x4 acc[2] = {{0,0,0,0},{0,0,0,0}};
    const __hip_bfloat16* wp = Wo + g * 8;
    #pragma unroll
    for (int kb = 0; kb < 8; kb++) {
        #pragma unroll
        for (int ot = 0; ot < 2; ot++) {
            bf16x8 bw = *reinterpret_cast<const bf16x8*>(wp + (size_t)(o0 + ot * 16 + li) * kC + kb * 32);
            acc[ot] = mfma16(a[kb], bw, acc[ot]);
        }
    }
    #pragma unroll
    for (int ot = 0; ot < 2; ot++) {
        int o = o0 + ot * 16 + li;
        *reinterpret_cast<f32x4*>(out + (size_t)(b * kC + o) * kM + m0 + 4 * g) = acc[ot];
    }
}

extern "C" void kernel_launch(void* const* d_in, const int* in_sizes, int n_in,
                              void* d_out, int out_size, void* d_ws, size_t ws_size,
                              hipStream_t stream) {
    const float* x     = (const float*)d_in[0];
    const float* gamma = (const float*)d_in[1];
    const float* beta  = (const float*)d_in[2];
    const float* rmean = (const float*)d_in[3];
    const float* rvar  = (const float*)d_in[4];
    const float* v_w   = (const float*)d_in[5];
    const float* z_w   = (const float*)d_in[6];
    const float* q_w   = (const float*)d_in[7];
    const float* o_w   = (const float*)d_in[8];
    float* out = (float*)d_out;

    char* wsb = (char*)d_ws;
    const size_t BMC = (size_t)kB * kM * kC;  // 1,179,648
    float* bninv   = (float*)wsb;             // [0, 1024)
    float* bnshift = bninv + 256;             // [1024, 2048)
    __hip_bfloat16* Wv16 = (__hip_bfloat16*)(wsb + 4096);
    __hip_bfloat16* Wz16 = Wv16 + 65536;
    __hip_bfloat16* Wq16 = Wz16 + 65536;
    __hip_bfloat16* Wo16 = Wq16 + 65536;
    __hip_bfloat16* Xnt  = Wo16 + 65536;
    __hip_bfloat16* V16  = Xnt + BMC;
    __hip_bfloat16* Zb16 = V16 + BMC;
    __hip_bfloat16* ZR16 = Zb16 + BMC;
    __hip_bfloat16* Qt16 = ZR16 + BMC;
    __hip_bfloat16* Y16  = Qt16 + BMC;   // total ~14.7 MB

    prep_bn<<<dim3(1), dim3(256), 0, stream>>>(gamma, beta, rmean, rvar, bninv, bnshift);
    pack_w<<<dim3(64, 4), dim3(256), 0, stream>>>(v_w, z_w, q_w, o_w, Wv16, Wz16, Wq16, Wo16);
    xnt_kernel<<<dim3(kM / 64, kC / 64, kB), dim3(256), 0, stream>>>(x, bninv, bnshift, Xnt);
    conv_gemm<<<dim3(kM / 16, kC / 64, 3 * kB), dim3(64), 0, stream>>>(
        Xnt, Wv16, Wz16, Wq16, V16, Zb16, Qt16);
    zr_kernel<<<dim3(kB * kM), dim3(256), 0, stream>>>(Zb16, ZR16);
    flash_attn_fused<<<dim3(kNT, kH, kB), dim3(256), 0, stream>>>(V16, ZR16, Qt16, Y16);
    conv_out_gemm<<<dim3(kM / 16, kC / 32, kB), dim3(64), 0, stream>>>(Y16, Wo16, out);
}